// Round 15
// baseline (86.537 us; speedup 1.0000x reference)
//
#include <hip/hip_runtime.h>
#include <hip/hip_bf16.h>
#include <stdint.h>

typedef float f32x16 __attribute__((ext_vector_type(16)));
typedef float f32x4  __attribute__((ext_vector_type(4)));
typedef short s16x8  __attribute__((ext_vector_type(8)));
typedef unsigned int u32x4 __attribute__((ext_vector_type(4)));

#define HWSZ   4096
#define NBATCH 4
#define LOG2E  1.44269504088896340736f

__device__ __forceinline__ unsigned short f2bf(float f) {
    unsigned u = __builtin_bit_cast(unsigned, f);
    u += 0x7FFFu + ((u >> 16) & 1u);          // RTNE
    return (unsigned short)(u >> 16);
}
__device__ __forceinline__ unsigned cvt_pk_bf16(float lo, float hi) {
    __hip_bfloat162 h = __float22bfloat162_rn(make_float2(lo, hi));
    return *reinterpret_cast<unsigned*>(&h);   // v_cvt_pk_bf16_f32; lo -> low 16
}
__device__ __forceinline__ float sigm2(float s) {   // rcp(1+exp2(-s)); K pre-scaled
    return __builtin_amdgcn_rcpf(1.f + __builtin_amdgcn_exp2f(-s));
}
__device__ __forceinline__ float bf_lo(unsigned u) {
    return __builtin_bit_cast(float, u << 16);
}
__device__ __forceinline__ float bf_hi(unsigned u) {
    return __builtin_bit_cast(float, u & 0xFFFF0000u);
}
__device__ __forceinline__ float bf2f(unsigned short u) {
    return __builtin_bit_cast(float, (unsigned)u << 16);
}

// ---------------- Kernel 1: MFMA projections (32 rows/WG, 512 WGs) ----------
template<bool WF32>
__global__ __launch_bounds__(256, 2) void proj_kernel(
    const float* __restrict__ x, const float* __restrict__ y,
    const float* __restrict__ W1, const float* __restrict__ b1,
    const float* __restrict__ W2, const float* __restrict__ b2,
    float* __restrict__ xq_f32,
    unsigned short* __restrict__ xqu_bf,
    unsigned short* __restrict__ xq_bf,
    unsigned short* __restrict__ yk_bf,
    unsigned short* __restrict__ ykT_bf)
{
    __shared__ unsigned short Xlds[32][136];
    __shared__ unsigned short Ylds[32][136];
    __shared__ unsigned short Tlds[128][40];

    const int t    = threadIdx.x;
    const int lane = t & 63;
    const int w    = t >> 6;
    const int l31  = lane & 31;
    const int g    = lane >> 5;
    const int r0   = blockIdx.x * 32;
    const int b    = r0 >> 12;
    const int j0   = r0 & (HWSZ - 1);

    #pragma unroll
    for (int i = 0; i < 4; ++i) {
        int li = t + 256 * i;
        int row = li >> 5, c = (li & 31) * 4;
        float4 vx = *(const float4*)(x + (size_t)(r0 + row) * 128 + c);
        float4 vy = *(const float4*)(y + (size_t)(r0 + row) * 128 + c);
        *(uint2*)&Xlds[row][c] = make_uint2(cvt_pk_bf16(vx.x, vx.y), cvt_pk_bf16(vx.z, vx.w));
        *(uint2*)&Ylds[row][c] = make_uint2(cvt_pk_bf16(vy.x, vy.y), cvt_pk_bf16(vy.z, vy.w));
    }
    __syncthreads();

    const int m  = w >> 1;
    const int fh = w & 1;
    const float* Wm = m ? W2 : W1;
    const float* bm = m ? b2 : b1;
    const unsigned short* A0 = m ? &Ylds[0][0] : &Xlds[0][0];

    f32x16 acc[2];
    #pragma unroll
    for (int i = 0; i < 16; ++i) { acc[0][i] = 0.f; acc[1][i] = 0.f; }

    #pragma unroll
    for (int ks = 0; ks < 8; ++ks) {
        s16x8 bfr[2];
        #pragma unroll
        for (int ft = 0; ft < 2; ++ft) {
            const float* wp = Wm + (size_t)(ks * 16 + g * 8) * 128 + fh * 64 + ft * 32 + l31;
            #pragma unroll
            for (int i = 0; i < 8; ++i)
                bfr[ft][i] = (short)f2bf(wp[(size_t)i * 128]);
        }
        s16x8 af = *(const s16x8*)(A0 + (size_t)l31 * 136 + ks * 16 + g * 8);
        acc[0] = __builtin_amdgcn_mfma_f32_32x32x16_bf16(af, bfr[0], acc[0], 0, 0, 0);
        acc[1] = __builtin_amdgcn_mfma_f32_32x32x16_bf16(af, bfr[1], acc[1], 0, 0, 0);
    }

    const float bias_v[2] = { bm[fh * 64 + l31], bm[fh * 64 + 32 + l31] };

    if (m == 0) {
        #pragma unroll
        for (int ft = 0; ft < 2; ++ft) {
            int f = fh * 64 + ft * 32 + l31;
            #pragma unroll
            for (int r = 0; r < 16; ++r) {
                int row = (r & 3) + 8 * (r >> 2) + 4 * g;
                float v = acc[ft][r] + bias_v[ft];
                size_t o = (size_t)(r0 + row) * 128 + f;
                if (WF32) xq_f32[o] = v;
                else      xqu_bf[o] = f2bf(v);
                xq_bf[o] = f2bf(v * LOG2E);
            }
        }
    } else {
        #pragma unroll
        for (int ft = 0; ft < 2; ++ft) {
            int f = fh * 64 + ft * 32 + l31;
            #pragma unroll
            for (int rg = 0; rg < 4; ++rg) {
                float p0 = acc[ft][4 * rg + 0] + bias_v[ft];
                float p1 = acc[ft][4 * rg + 1] + bias_v[ft];
                float p2 = acc[ft][4 * rg + 2] + bias_v[ft];
                float p3 = acc[ft][4 * rg + 3] + bias_v[ft];
                int jb = 8 * rg + 4 * g;
                *(uint2*)&Tlds[f][jb] = make_uint2(cvt_pk_bf16(p0, p1), cvt_pk_bf16(p2, p3));
                size_t o = (size_t)(r0 + jb) * 128 + f;
                yk_bf[o]       = f2bf(p0);
                yk_bf[o + 128] = f2bf(p1);
                yk_bf[o + 256] = f2bf(p2);
                yk_bf[o + 384] = f2bf(p3);
            }
        }
    }
    __syncthreads();

    {
        int f  = t >> 1;
        int jh = (t & 1) * 16;
        unsigned short* dst = ykT_bf + ((size_t)(b * 128 + f)) * HWSZ + j0 + jh;
        #pragma unroll
        for (int c = 0; c < 2; ++c)
            *(s16x8*)(dst + c * 8) = *(const s16x8*)&Tlds[f][jh + c * 8];
    }
}

// ---------------- shared attention LDS geometry ----------------
#define KT_STR   136
#define VT_STR   72
#define KT_BYTES (64 * KT_STR * 2)     // 17408
#define VT_BYTES (128 * VT_STR * 2)    // 18432
#define BUF_BYTES (KT_BYTES + VT_BYTES)

// ---------------- Kernel 2a: QBLK=128, 4-split, K-from-global-prefetched ----
// LDS-BW relief: K never touches LDS. Each wave prefetches its 16 kf frags for
// tile t+1 from global (L1/L2-hit) into the SAME registers right after their
// last read in tile t (end of QK1) -> ~700cy lead. LDS = V dbuf only (36.9KB):
// LDS traffic 320->160 KB/CU-iter (was the measured bottleneck).
__global__ __launch_bounds__(256, 2) void attn128_kernel(
    const unsigned short* __restrict__ Kbf,   // xq_bf (log2e-scaled) [b][j][128]
    const unsigned short* __restrict__ Qbf,   // yk_bf  [b][q][128]
    const unsigned short* __restrict__ Vtbf,  // ykT_bf [b][128][4096]
    unsigned* __restrict__ outp)              // packed partials (4 x NELEM/2 u32)
{
    __shared__ __align__(16) unsigned short Vlds[2][128 * VT_STR];  // 36864 B

    const int t    = threadIdx.x;
    const int lane = t & 63;
    const int qt   = t >> 6;
    const int l31  = lane & 31;
    const int g    = lane >> 5;

    const int split  = blockIdx.x >> 7;       // 0..3
    const int r      = blockIdx.x & 127;
    const int b      = r >> 5;
    const int qb     = (r & 31) * 128;
    const int jBegin = split * (HWSZ / 4);
    const int nt     = (HWSZ / 4) / 64;       // 16

    s16x8 qfrag[8];
    {
        const unsigned short* qp =
            Qbf + (((size_t)(b * HWSZ + qb + 32 * qt + l31)) << 7) + g * 8;
        #pragma unroll
        for (int fs = 0; fs < 8; ++fs)
            qfrag[fs] = *(const s16x8*)(qp + fs * 16);
    }

    f32x16 acc[4];
    #pragma unroll
    for (int ft = 0; ft < 4; ++ft)
        #pragma unroll
        for (int i = 0; i < 16; ++i) acc[ft][i] = 0.f;

    f32x16 zv;                                 // hoisted zero seed for QK chains
    #pragma unroll
    for (int i = 0; i < 16; ++i) zv[i] = 0.f;

    const unsigned short* Kbase = Kbf  + (((size_t)b * HWSZ) << 7);
    const unsigned short* Vbase = Vtbf + (((size_t)b) << 7) * HWSZ;

    // per-lane K pointer (row jBegin + jt*32 + l31, col fs*16 + g*8)
    const unsigned short* kPtr = Kbase + (size_t)(jBegin + l31) * 128 + g * 8;

    // K frags for the CURRENT tile, prefetched one tile ahead
    s16x8 kf[16];
    #pragma unroll
    for (int jt = 0; jt < 2; ++jt)
        #pragma unroll
        for (int fs = 0; fs < 8; ++fs)
            kf[jt * 8 + fs] = *(const s16x8*)(kPtr + jt * 32 * 128 + fs * 16);

    const unsigned short* vSrc = Vbase + (size_t)(t >> 3) * HWSZ + jBegin + (t & 7) * 8;
    const int vDst = (t >> 3) * VT_STR + (t & 7) * 8;

    {   // prologue: stage V tile 0 into buf 0
        #pragma unroll
        for (int i = 0; i < 4; ++i)
            *(s16x8*)(&Vlds[0][0] + vDst + i * 32 * VT_STR) =
                *(const s16x8*)(vSrc + (size_t)i * 32 * HWSZ);
    }
    __syncthreads();

    int c = 0;
    for (int it = 0; it < nt; ++it) {
        const bool pre = (it + 1 < nt);
        const unsigned short* Vl = &Vlds[c][0];

        // ---- stage A: QK0 (kf[0..7]), 2 independent chains seeded from zv ----
        f32x16 s0a, s0b;
        __builtin_amdgcn_s_setprio(1);
        #pragma unroll
        for (int fs = 0; fs < 4; ++fs) {
            s0a = __builtin_amdgcn_mfma_f32_32x32x16_bf16(kf[fs],     qfrag[fs],
                      fs == 0 ? zv : s0a, 0, 0, 0);
            s0b = __builtin_amdgcn_mfma_f32_32x32x16_bf16(kf[fs + 4], qfrag[fs + 4],
                      fs == 0 ? zv : s0b, 0, 0, 0);
        }
        __builtin_amdgcn_s_setprio(0);

        // issue-early V staging loads for tile it+1
        s16x8 vr[4];
        if (pre) {
            vSrc += 64;
            #pragma unroll
            for (int i = 0; i < 4; ++i)
                vr[i] = *(const s16x8*)(vSrc + (size_t)i * 32 * HWSZ);
        }

        // ---- stage B: QK1 MFMAs (kf[8..15]) || sigmoid0 ----
        f32x16 s1a, s1b;
        unsigned W0[2][4], W1[2][4];
        #pragma unroll
        for (int fs = 0; fs < 4; ++fs) {
            s1a = __builtin_amdgcn_mfma_f32_32x32x16_bf16(kf[8 + fs],     qfrag[fs],
                      fs == 0 ? zv : s1a, 0, 0, 0);
            s1b = __builtin_amdgcn_mfma_f32_32x32x16_bf16(kf[8 + fs + 4], qfrag[fs + 4],
                      fs == 0 ? zv : s1b, 0, 0, 0);
            const int rg = fs;
            float p0 = sigm2(s0a[4 * rg + 0] + s0b[4 * rg + 0]);
            float p1 = sigm2(s0a[4 * rg + 1] + s0b[4 * rg + 1]);
            float p2 = sigm2(s0a[4 * rg + 2] + s0b[4 * rg + 2]);
            float p3 = sigm2(s0a[4 * rg + 3] + s0b[4 * rg + 3]);
            W0[0][rg] = cvt_pk_bf16(p0, p1);
            W1[0][rg] = cvt_pk_bf16(p2, p3);
        }

        // ---- kf dead: prefetch kf for tile it+1 from global (~2 phases lead) ----
        if (pre) {
            kPtr += 64 * 128;
            #pragma unroll
            for (int jt = 0; jt < 2; ++jt)
                #pragma unroll
                for (int fs = 0; fs < 8; ++fs)
                    kf[jt * 8 + fs] = *(const s16x8*)(kPtr + jt * 32 * 128 + fs * 16);
        }

        // ---- stage C: PV0 MFMAs || sigmoid1 ----
        __builtin_amdgcn_s_setprio(1);
        #pragma unroll
        for (int s2 = 0; s2 < 2; ++s2) {
            unsigned a0 = W0[0][2 * s2], b0 = W0[0][2 * s2 + 1];
            unsigned a1 = W1[0][2 * s2], b1 = W1[0][2 * s2 + 1];
            asm("v_permlane32_swap_b32 %0, %1" : "+v"(a0), "+v"(b0));
            asm("v_permlane32_swap_b32 %0, %1" : "+v"(a1), "+v"(b1));
            u32x4 pw;
            pw[0] = a0; pw[1] = a1; pw[2] = b0; pw[3] = b1;
            s16x8 pf = __builtin_bit_cast(s16x8, pw);
            #pragma unroll
            for (int ft = 0; ft < 4; ++ft) {
                s16x8 vf = *(const s16x8*)(Vl + (size_t)(32 * ft + l31) * VT_STR + s2 * 16 + g * 8);
                acc[ft] = __builtin_amdgcn_mfma_f32_32x32x16_bf16(pf, vf, acc[ft], 0, 0, 0);
            }
            #pragma unroll
            for (int h = 0; h < 2; ++h) {
                const int rg = 2 * s2 + h;
                float p0 = sigm2(s1a[4 * rg + 0] + s1b[4 * rg + 0]);
                float p1 = sigm2(s1a[4 * rg + 1] + s1b[4 * rg + 1]);
                float p2 = sigm2(s1a[4 * rg + 2] + s1b[4 * rg + 2]);
                float p3 = sigm2(s1a[4 * rg + 3] + s1b[4 * rg + 3]);
                W0[1][rg] = cvt_pk_bf16(p0, p1);
                W1[1][rg] = cvt_pk_bf16(p2, p3);
            }
        }

        // ---- stage D: PV1 ----
        #pragma unroll
        for (int s2 = 0; s2 < 2; ++s2) {
            unsigned a0 = W0[1][2 * s2], b0 = W0[1][2 * s2 + 1];
            unsigned a1 = W1[1][2 * s2], b1 = W1[1][2 * s2 + 1];
            asm("v_permlane32_swap_b32 %0, %1" : "+v"(a0), "+v"(b0));
            asm("v_permlane32_swap_b32 %0, %1" : "+v"(a1), "+v"(b1));
            u32x4 pw;
            pw[0] = a0; pw[1] = a1; pw[2] = b0; pw[3] = b1;
            s16x8 pf = __builtin_bit_cast(s16x8, pw);
            const int ks = 2 + s2;
            #pragma unroll
            for (int ft = 0; ft < 4; ++ft) {
                s16x8 vf = *(const s16x8*)(Vl + (size_t)(32 * ft + l31) * VT_STR + ks * 16 + g * 8);
                acc[ft] = __builtin_amdgcn_mfma_f32_32x32x16_bf16(pf, vf, acc[ft], 0, 0, 0);
            }
        }
        __builtin_amdgcn_s_setprio(0);

        // ---- write-late V into other buffer ----
        if (pre) {
            #pragma unroll
            for (int i = 0; i < 4; ++i)
                *(s16x8*)(&Vlds[c ^ 1][0] + vDst + i * 32 * VT_STR) = vr[i];
        }
        __syncthreads();
        c ^= 1;
    }

    // ---- epilogue: bf16x2-packed partial (row pairs r2, r2+1) ----
    unsigned* op = outp + (size_t)split * ((size_t)NBATCH * HWSZ * 64);
    #pragma unroll
    for (int ft = 0; ft < 4; ++ft)
    #pragma unroll
    for (int pr = 0; pr < 8; ++pr) {
        int r2 = 2 * pr;
        int row = (r2 & 3) + 8 * (r2 >> 2) + 4 * g;      // even
        int q = qb + 32 * qt + row;
        unsigned v = cvt_pk_bf16(acc[ft][r2], acc[ft][r2 + 1]);
        op[((size_t)(b * HWSZ + q) >> 1) * 128 + 32 * ft + l31] = v;
    }
}

// ---------------- Kernel 2b: QBLK=64 fallback (2-split / no-split) ----------------
template<bool SPLIT>
__global__ __launch_bounds__(256, 2) void attn_kernel(
    const unsigned short* __restrict__ Kbf,
    const unsigned short* __restrict__ Qbf,
    const unsigned short* __restrict__ Vtbf,
    const float* __restrict__ resid,
    float* __restrict__ outp)
{
    __shared__ __align__(16) char smem[2 * BUF_BYTES];

    const int t    = threadIdx.x;
    const int lane = t & 63;
    const int w    = t >> 6;
    const int qt   = w & 1;
    const int jt   = w >> 1;
    const int l31  = lane & 31;
    const int g    = lane >> 5;

    int bid = blockIdx.x;
    int half = 0;
    if (SPLIT) { half = bid >> 8; bid &= 255; }
    const int b      = bid >> 6;
    const int qb     = (bid & 63) * 64;
    const int jBegin = half * (HWSZ / 2);
    const int nt     = (SPLIT ? HWSZ / 2 : HWSZ) / 64;

    s16x8 qfrag[8];
    {
        const unsigned short* qp =
            Qbf + (((size_t)(b * HWSZ + qb + 32 * qt + l31)) << 7) + g * 8;
        #pragma unroll
        for (int fs = 0; fs < 8; ++fs)
            qfrag[fs] = *(const s16x8*)(qp + fs * 16);
    }

    f32x16 acc[4];
    #pragma unroll
    for (int ft = 0; ft < 4; ++ft)
        #pragma unroll
        for (int i = 0; i < 16; ++i) acc[ft][i] = 0.f;

    const unsigned short* Kbase = Kbf  + (((size_t)b * HWSZ) << 7);
    const unsigned short* Vbase = Vtbf + (((size_t)b) << 7) * HWSZ;

    const unsigned short* kSrc = Kbase + (size_t)(jBegin + (t >> 4)) * 128 + (t & 15) * 8;
    const unsigned short* vSrc = Vbase + (size_t)(t >> 3) * HWSZ + jBegin + (t & 7) * 8;
    const int kDst = (t >> 4) * KT_STR + (t & 15) * 8;
    const int vDst = (t >> 3) * VT_STR + (t & 7) * 8;

    {
        unsigned short* Kl = (unsigned short*)smem;
        unsigned short* Vl = (unsigned short*)(smem + KT_BYTES);
        #pragma unroll
        for (int i = 0; i < 4; ++i)
            *(s16x8*)(Kl + kDst + i * 16 * KT_STR) = *(const s16x8*)(kSrc + (size_t)i * 2048);
        #pragma unroll
        for (int i = 0; i < 4; ++i)
            *(s16x8*)(Vl + vDst + i * 32 * VT_STR) = *(const s16x8*)(vSrc + (size_t)i * 32 * HWSZ);
    }
    __syncthreads();

    int c = 0;
    for (int it = 0; it < nt; ++it) {
        const bool pre = (it + 1 < nt);
        s16x8 kr[4], vr[4];
        if (pre) {
            kSrc += 64 * 128;
            vSrc += 64;
            #pragma unroll
            for (int i = 0; i < 4; ++i)
                kr[i] = *(const s16x8*)(kSrc + (size_t)i * 2048);
            #pragma unroll
            for (int i = 0; i < 4; ++i)
                vr[i] = *(const s16x8*)(vSrc + (size_t)i * 32 * HWSZ);
        }

        const unsigned short* Kl = (const unsigned short*)(smem + c * BUF_BYTES);
        const unsigned short* Vl = (const unsigned short*)(smem + c * BUF_BYTES + KT_BYTES);

        f32x16 sa, sb;
        #pragma unroll
        for (int i = 0; i < 16; ++i) { sa[i] = 0.f; sb[i] = 0.f; }
        const unsigned short* Krow = Kl + (size_t)(32 * jt + l31) * KT_STR + g * 8;
        __builtin_amdgcn_s_setprio(1);
        #pragma unroll
        for (int fs = 0; fs < 4; ++fs) {
            sa = __builtin_amdgcn_mfma_f32_32x32x16_bf16(
                     *(const s16x8*)(Krow + fs * 16), qfrag[fs], sa, 0, 0, 0);
            sb = __builtin_amdgcn_mfma_f32_32x32x16_bf16(
                     *(const s16x8*)(Krow + (fs + 4) * 16), qfrag[fs + 4], sb, 0, 0, 0);
        }
        __builtin_amdgcn_s_setprio(0);

        unsigned W0[4], W1[4];
        #pragma unroll
        for (int rg = 0; rg < 4; ++rg) {
            float p0 = sigm2(sa[4 * rg + 0] + sb[4 * rg + 0]);
            float p1 = sigm2(sa[4 * rg + 1] + sb[4 * rg + 1]);
            float p2 = sigm2(sa[4 * rg + 2] + sb[4 * rg + 2]);
            float p3 = sigm2(sa[4 * rg + 3] + sb[4 * rg + 3]);
            W0[rg] = cvt_pk_bf16(p0, p1);
            W1[rg] = cvt_pk_bf16(p2, p3);
        }

        #pragma unroll
        for (int s2 = 0; s2 < 2; ++s2) {
            unsigned a0 = W0[2 * s2], b0 = W0[2 * s2 + 1];
            unsigned a1 = W1[2 * s2], b1 = W1[2 * s2 + 1];
            asm("v_permlane32_swap_b32 %0, %1" : "+v"(a0), "+v"(b0));
            asm("v_permlane32_swap_b32 %0, %1" : "+v"(a1), "+v"(b1));
            u32x4 pw;
            pw[0] = a0; pw[1] = a1; pw[2] = b0; pw[3] = b1;
            s16x8 pf = __builtin_bit_cast(s16x8, pw);
            const int ks = 2 * jt + s2;
            __builtin_amdgcn_s_setprio(1);
            #pragma unroll
            for (int ft = 0; ft < 4; ++ft) {
                s16x8 vf = *(const s16x8*)(Vl + (size_t)(32 * ft + l31) * VT_STR + ks * 16 + g * 8);
                acc[ft] = __builtin_amdgcn_mfma_f32_32x32x16_bf16(pf, vf, acc[ft], 0, 0, 0);
            }
            __builtin_amdgcn_s_setprio(0);
        }

        if (pre) {
            unsigned short* Kd = (unsigned short*)(smem + (c ^ 1) * BUF_BYTES);
            unsigned short* Vd = (unsigned short*)(smem + (c ^ 1) * BUF_BYTES + KT_BYTES);
            #pragma unroll
            for (int i = 0; i < 4; ++i)
                *(s16x8*)(Kd + kDst + i * 16 * KT_STR) = kr[i];
            #pragma unroll
            for (int i = 0; i < 4; ++i)
                *(s16x8*)(Vd + vDst + i * 32 * VT_STR) = vr[i];
        }
        __syncthreads();
        c ^= 1;
    }

    float* red = (float*)smem;
    if (jt == 1) {
        #pragma unroll
        for (int ft = 0; ft < 4; ++ft)
        #pragma unroll
        for (int r = 0; r < 16; ++r) {
            int row = (r & 3) + 8 * (r >> 2) + 4 * g;
            red[qt * 4096 + row * 128 + 32 * ft + l31] = acc[ft][r];
        }
    }
    __syncthreads();
    if (jt == 0) {
        float* op = outp + (SPLIT ? (size_t)half * ((size_t)NBATCH * HWSZ * 128) : 0);
        #pragma unroll
        for (int ft = 0; ft < 4; ++ft)
        #pragma unroll
        for (int r = 0; r < 16; ++r) {
            int row = (r & 3) + 8 * (r >> 2) + 4 * g;
            float v = acc[ft][r] + red[qt * 4096 + row * 128 + 32 * ft + l31];
            int q = qb + 32 * qt + row;
            size_t o = (((size_t)(b * HWSZ + q)) << 7) + 32 * ft + l31;
            if (SPLIT) op[o] = v;
            else       op[o] = v + resid[o];
        }
    }
}

// ---------------- Kernel 3: partial reduce + residual ----------------
__global__ __launch_bounds__(256, 1) void reduce2_kernel(
    const float* __restrict__ p0, const float* __restrict__ p1, float* outp)
{
    int i = blockIdx.x * 256 + threadIdx.x;
    f32x4 a = ((const f32x4*)p0)[i];
    f32x4 b = ((const f32x4*)p1)[i];
    f32x4 c = ((f32x4*)outp)[i];
    ((f32x4*)outp)[i] = a + b + c;
}

__global__ __launch_bounds__(256, 1) void reduce4bf_kernel(
    const unsigned* __restrict__ parts, const unsigned short* __restrict__ xqu,
    float* __restrict__ outp)
{
    const size_t NU = (size_t)NBATCH * HWSZ * 64;
    size_t j0 = ((size_t)blockIdx.x * 256 + threadIdx.x) * 4;
    f32x4 lo, hi;
    #pragma unroll
    for (int e = 0; e < 4; ++e) { lo[e] = 0.f; hi[e] = 0.f; }
    #pragma unroll
    for (int k = 0; k < 4; ++k) {
        u32x4 v = *(const u32x4*)(parts + k * NU + j0);
        #pragma unroll
        for (int e = 0; e < 4; ++e) {
            lo[e] += bf_lo(v[e]);
            hi[e] += bf_hi(v[e]);
        }
    }
    size_t p  = j0 >> 7;
    int    f0 = (int)(j0 & 127);
    size_t o0 = (p * 2) * 128 + f0;
    const ushort4 r0 = *(const ushort4*)(xqu + o0);
    const ushort4 r1 = *(const ushort4*)(xqu + o0 + 128);
    lo[0] += bf2f(r0.x); lo[1] += bf2f(r0.y); lo[2] += bf2f(r0.z); lo[3] += bf2f(r0.w);
    hi[0] += bf2f(r1.x); hi[1] += bf2f(r1.y); hi[2] += bf2f(r1.z); hi[3] += bf2f(r1.w);
    *(f32x4*)(outp + o0)       = lo;
    *(f32x4*)(outp + o0 + 128) = hi;
}

extern "C" void kernel_launch(void* const* d_in, const int* in_sizes, int n_in,
                              void* d_out, int out_size, void* d_ws, size_t ws_size,
                              hipStream_t stream) {
    const float* x  = (const float*)d_in[0];
    const float* y  = (const float*)d_in[1];
    const float* W1 = (const float*)d_in[2];
    const float* b1 = (const float*)d_in[3];
    const float* W2 = (const float*)d_in[4];
    const float* b2 = (const float*)d_in[5];
    float* out = (float*)d_out;

    const size_t NELEM = (size_t)NBATCH * HWSZ * 128;   // 2,097,152
    unsigned short* xq_bf  = (unsigned short*)d_ws;
    unsigned short* yk_bf  = xq_bf + NELEM;
    unsigned short* ykT_bf = yk_bf + NELEM;
    unsigned short* xqu_bf = ykT_bf + NELEM;
    unsigned* partu = (unsigned*)(xqu_bf + NELEM);
    float* part = (float*)(ykT_bf + NELEM);

    if (ws_size >= NELEM * 16) {                 // main: K-prefetch attn, bf16 partials
        proj_kernel<false><<<(int)(NBATCH * HWSZ / 32), 256, 0, stream>>>(
            x, y, W1, b1, W2, b2, nullptr, xqu_bf, xq_bf, yk_bf, ykT_bf);
        attn128_kernel<<<512, 256, 0, stream>>>(xq_bf, yk_bf, ykT_bf, partu);
        reduce4bf_kernel<<<(int)(NELEM / 2048), 256, 0, stream>>>(partu, xqu_bf, out);
    } else if (ws_size >= NELEM * 14) {          // QBLK=64, 2-split (f32 partials)
        proj_kernel<true><<<(int)(NBATCH * HWSZ / 32), 256, 0, stream>>>(
            x, y, W1, b1, W2, b2, out, nullptr, xq_bf, yk_bf, ykT_bf);
        attn_kernel<true><<<512, 256, 0, stream>>>(xq_bf, yk_bf, ykT_bf, out, part);
        reduce2_kernel<<<(int)(NELEM / 1024), 256, 0, stream>>>(part, part + NELEM, out);
    } else {
        proj_kernel<true><<<(int)(NBATCH * HWSZ / 32), 256, 0, stream>>>(
            x, y, W1, b1, W2, b2, out, nullptr, xq_bf, yk_bf, ykT_bf);
        attn_kernel<false><<<256, 256, 0, stream>>>(xq_bf, yk_bf, ykT_bf, out, out);
    }
}

// Round 16
// 60.879 us; speedup vs baseline: 1.4215x; 1.4215x over previous
//
#include <hip/hip_runtime.h>
#include <hip/hip_bf16.h>
#include <stdint.h>

typedef float f32x16 __attribute__((ext_vector_type(16)));
typedef float f32x4  __attribute__((ext_vector_type(4)));
typedef short s16x8  __attribute__((ext_vector_type(8)));
typedef unsigned int u32x4 __attribute__((ext_vector_type(4)));

#define HWSZ   4096
#define NBATCH 4
#define LOG2E  1.44269504088896340736f

__device__ __forceinline__ unsigned short f2bf(float f) {
    unsigned u = __builtin_bit_cast(unsigned, f);
    u += 0x7FFFu + ((u >> 16) & 1u);          // RTNE
    return (unsigned short)(u >> 16);
}
__device__ __forceinline__ unsigned cvt_pk_bf16(float lo, float hi) {
    __hip_bfloat162 h = __float22bfloat162_rn(make_float2(lo, hi));
    return *reinterpret_cast<unsigned*>(&h);   // v_cvt_pk_bf16_f32; lo -> low 16
}
__device__ __forceinline__ float sigm2(float s) {   // rcp(1+exp2(-s)); K pre-scaled
    return __builtin_amdgcn_rcpf(1.f + __builtin_amdgcn_exp2f(-s));
}
__device__ __forceinline__ float bf_lo(unsigned u) {
    return __builtin_bit_cast(float, u << 16);
}
__device__ __forceinline__ float bf_hi(unsigned u) {
    return __builtin_bit_cast(float, u & 0xFFFF0000u);
}
__device__ __forceinline__ float bf2f(unsigned short u) {
    return __builtin_bit_cast(float, (unsigned)u << 16);
}

// ---------------- Kernel 1: MFMA projections (32 rows/WG, 512 WGs) ----------
template<bool WF32>
__global__ __launch_bounds__(256, 2) void proj_kernel(
    const float* __restrict__ x, const float* __restrict__ y,
    const float* __restrict__ W1, const float* __restrict__ b1,
    const float* __restrict__ W2, const float* __restrict__ b2,
    float* __restrict__ xq_f32,
    unsigned short* __restrict__ xqu_bf,
    unsigned short* __restrict__ xq_bf,
    unsigned short* __restrict__ yk_bf,
    unsigned short* __restrict__ ykT_bf)
{
    __shared__ unsigned short Xlds[32][136];
    __shared__ unsigned short Ylds[32][136];
    __shared__ unsigned short Tlds[128][40];

    const int t    = threadIdx.x;
    const int lane = t & 63;
    const int w    = t >> 6;
    const int l31  = lane & 31;
    const int g    = lane >> 5;
    const int r0   = blockIdx.x * 32;
    const int b    = r0 >> 12;
    const int j0   = r0 & (HWSZ - 1);

    #pragma unroll
    for (int i = 0; i < 4; ++i) {
        int li = t + 256 * i;
        int row = li >> 5, c = (li & 31) * 4;
        float4 vx = *(const float4*)(x + (size_t)(r0 + row) * 128 + c);
        float4 vy = *(const float4*)(y + (size_t)(r0 + row) * 128 + c);
        *(uint2*)&Xlds[row][c] = make_uint2(cvt_pk_bf16(vx.x, vx.y), cvt_pk_bf16(vx.z, vx.w));
        *(uint2*)&Ylds[row][c] = make_uint2(cvt_pk_bf16(vy.x, vy.y), cvt_pk_bf16(vy.z, vy.w));
    }
    __syncthreads();

    const int m  = w >> 1;
    const int fh = w & 1;
    const float* Wm = m ? W2 : W1;
    const float* bm = m ? b2 : b1;
    const unsigned short* A0 = m ? &Ylds[0][0] : &Xlds[0][0];

    f32x16 acc[2];
    #pragma unroll
    for (int i = 0; i < 16; ++i) { acc[0][i] = 0.f; acc[1][i] = 0.f; }

    #pragma unroll
    for (int ks = 0; ks < 8; ++ks) {
        s16x8 bfr[2];
        #pragma unroll
        for (int ft = 0; ft < 2; ++ft) {
            const float* wp = Wm + (size_t)(ks * 16 + g * 8) * 128 + fh * 64 + ft * 32 + l31;
            #pragma unroll
            for (int i = 0; i < 8; ++i)
                bfr[ft][i] = (short)f2bf(wp[(size_t)i * 128]);
        }
        s16x8 af = *(const s16x8*)(A0 + (size_t)l31 * 136 + ks * 16 + g * 8);
        acc[0] = __builtin_amdgcn_mfma_f32_32x32x16_bf16(af, bfr[0], acc[0], 0, 0, 0);
        acc[1] = __builtin_amdgcn_mfma_f32_32x32x16_bf16(af, bfr[1], acc[1], 0, 0, 0);
    }

    const float bias_v[2] = { bm[fh * 64 + l31], bm[fh * 64 + 32 + l31] };

    if (m == 0) {
        #pragma unroll
        for (int ft = 0; ft < 2; ++ft) {
            int f = fh * 64 + ft * 32 + l31;
            #pragma unroll
            for (int r = 0; r < 16; ++r) {
                int row = (r & 3) + 8 * (r >> 2) + 4 * g;
                float v = acc[ft][r] + bias_v[ft];
                size_t o = (size_t)(r0 + row) * 128 + f;
                if (WF32) xq_f32[o] = v;
                else      xqu_bf[o] = f2bf(v);
                xq_bf[o] = f2bf(v * LOG2E);
            }
        }
    } else {
        #pragma unroll
        for (int ft = 0; ft < 2; ++ft) {
            int f = fh * 64 + ft * 32 + l31;
            #pragma unroll
            for (int rg = 0; rg < 4; ++rg) {
                float p0 = acc[ft][4 * rg + 0] + bias_v[ft];
                float p1 = acc[ft][4 * rg + 1] + bias_v[ft];
                float p2 = acc[ft][4 * rg + 2] + bias_v[ft];
                float p3 = acc[ft][4 * rg + 3] + bias_v[ft];
                int jb = 8 * rg + 4 * g;
                *(uint2*)&Tlds[f][jb] = make_uint2(cvt_pk_bf16(p0, p1), cvt_pk_bf16(p2, p3));
                size_t o = (size_t)(r0 + jb) * 128 + f;
                yk_bf[o]       = f2bf(p0);
                yk_bf[o + 128] = f2bf(p1);
                yk_bf[o + 256] = f2bf(p2);
                yk_bf[o + 384] = f2bf(p3);
            }
        }
    }
    __syncthreads();

    {
        int f  = t >> 1;
        int jh = (t & 1) * 16;
        unsigned short* dst = ykT_bf + ((size_t)(b * 128 + f)) * HWSZ + j0 + jh;
        #pragma unroll
        for (int c = 0; c < 2; ++c)
            *(s16x8*)(dst + c * 8) = *(const s16x8*)&Tlds[f][jh + c * 8];
    }
}

// ---------------- shared attention LDS geometry ----------------
#define KT_STR   136
#define VT_STR   72
#define KT_BYTES (64 * KT_STR * 2)     // 17408
#define VT_BYTES (128 * VT_STR * 2)    // 18432
#define BUF_BYTES (KT_BYTES + VT_BYTES)

// ---------------- Kernel 2a: QBLK=128, 4-split, phase-interleaved (R12) ------
// VERIFIED BEST (42.7us). K+V both LDS double-buffered; reg-staged issue-early/
// write-late; 4 overlapped stages QK0 -> {QK1||sig0} -> {PV0||sig1} -> PV1.
// Do NOT: (256,4) [spills], K-direct-from-global [latency, 2x confirmed],
// 2-wave/64q [VGPR->1 wave/SIMD], K-single-buffer+reg-cap [spills].
__global__ __launch_bounds__(256, 2) void attn128_kernel(
    const unsigned short* __restrict__ Kbf,   // xq_bf (log2e-scaled) [b][j][128]
    const unsigned short* __restrict__ Qbf,   // yk_bf  [b][q][128]
    const unsigned short* __restrict__ Vtbf,  // ykT_bf [b][128][4096]
    unsigned* __restrict__ outp)              // packed partials (4 x NELEM/2 u32)
{
    __shared__ __align__(16) char smem[2 * BUF_BYTES];

    const int t    = threadIdx.x;
    const int lane = t & 63;
    const int qt   = t >> 6;
    const int l31  = lane & 31;
    const int g    = lane >> 5;

    const int split  = blockIdx.x >> 7;       // 0..3
    const int r      = blockIdx.x & 127;
    const int b      = r >> 5;
    const int qb     = (r & 31) * 128;
    const int jBegin = split * (HWSZ / 4);
    const int nt     = (HWSZ / 4) / 64;       // 16

    s16x8 qfrag[8];
    {
        const unsigned short* qp =
            Qbf + (((size_t)(b * HWSZ + qb + 32 * qt + l31)) << 7) + g * 8;
        #pragma unroll
        for (int fs = 0; fs < 8; ++fs)
            qfrag[fs] = *(const s16x8*)(qp + fs * 16);
    }

    f32x16 acc[4];
    #pragma unroll
    for (int ft = 0; ft < 4; ++ft)
        #pragma unroll
        for (int i = 0; i < 16; ++i) acc[ft][i] = 0.f;

    f32x16 zv;                                 // hoisted zero seed for QK chains
    #pragma unroll
    for (int i = 0; i < 16; ++i) zv[i] = 0.f;

    const unsigned short* Kbase = Kbf  + (((size_t)b * HWSZ) << 7);
    const unsigned short* Vbase = Vtbf + (((size_t)b) << 7) * HWSZ;

    const unsigned short* kSrc = Kbase + (size_t)(jBegin + (t >> 4)) * 128 + (t & 15) * 8;
    const unsigned short* vSrc = Vbase + (size_t)(t >> 3) * HWSZ + jBegin + (t & 7) * 8;
    const int kDst = (t >> 4) * KT_STR + (t & 15) * 8;
    const int vDst = (t >> 3) * VT_STR + (t & 7) * 8;

    {   // prologue: stage tile 0 into buf 0
        unsigned short* Kl = (unsigned short*)smem;
        unsigned short* Vl = (unsigned short*)(smem + KT_BYTES);
        #pragma unroll
        for (int i = 0; i < 4; ++i)
            *(s16x8*)(Kl + kDst + i * 16 * KT_STR) = *(const s16x8*)(kSrc + (size_t)i * 2048);
        #pragma unroll
        for (int i = 0; i < 4; ++i)
            *(s16x8*)(Vl + vDst + i * 32 * VT_STR) = *(const s16x8*)(vSrc + (size_t)i * 32 * HWSZ);
    }
    __syncthreads();

    int c = 0;
    for (int it = 0; it < nt; ++it) {
        const bool pre = (it + 1 < nt);
        const unsigned short* Kl = (const unsigned short*)(smem + c * BUF_BYTES);
        const unsigned short* Vl = (const unsigned short*)(smem + c * BUF_BYTES + KT_BYTES);

        // ---- stage A: QK0 (jt=0), 2 independent chains seeded from zv ----
        s16x8 kf0[8], kf1[8];
        {
            const unsigned short* Krow = Kl + (size_t)l31 * KT_STR + g * 8;
            #pragma unroll
            for (int fs = 0; fs < 8; ++fs)
                kf0[fs] = *(const s16x8*)(Krow + fs * 16);
        }
        f32x16 s0a, s0b;
        __builtin_amdgcn_s_setprio(1);
        #pragma unroll
        for (int fs = 0; fs < 4; ++fs) {
            s0a = __builtin_amdgcn_mfma_f32_32x32x16_bf16(kf0[fs],     qfrag[fs],
                      fs == 0 ? zv : s0a, 0, 0, 0);
            s0b = __builtin_amdgcn_mfma_f32_32x32x16_bf16(kf0[fs + 4], qfrag[fs + 4],
                      fs == 0 ? zv : s0b, 0, 0, 0);
        }
        __builtin_amdgcn_s_setprio(0);

        // K-frags for jt=1 + mid-iter staging issue (independent of QK0)
        {
            const unsigned short* Krow = Kl + (size_t)(32 + l31) * KT_STR + g * 8;
            #pragma unroll
            for (int fs = 0; fs < 8; ++fs)
                kf1[fs] = *(const s16x8*)(Krow + fs * 16);
        }
        s16x8 kr[4], vr[4];
        if (pre) {
            kSrc += 64 * 128;
            vSrc += 64;
            #pragma unroll
            for (int i = 0; i < 4; ++i)
                kr[i] = *(const s16x8*)(kSrc + (size_t)i * 2048);
            #pragma unroll
            for (int i = 0; i < 4; ++i)
                vr[i] = *(const s16x8*)(vSrc + (size_t)i * 32 * HWSZ);
        }

        // ---- stage B: QK1 MFMAs || sigmoid0 ----
        f32x16 s1a, s1b;
        unsigned W0[2][4], W1[2][4];
        #pragma unroll
        for (int fs = 0; fs < 4; ++fs) {
            s1a = __builtin_amdgcn_mfma_f32_32x32x16_bf16(kf1[fs],     qfrag[fs],
                      fs == 0 ? zv : s1a, 0, 0, 0);
            s1b = __builtin_amdgcn_mfma_f32_32x32x16_bf16(kf1[fs + 4], qfrag[fs + 4],
                      fs == 0 ? zv : s1b, 0, 0, 0);
            const int rg = fs;
            float p0 = sigm2(s0a[4 * rg + 0] + s0b[4 * rg + 0]);
            float p1 = sigm2(s0a[4 * rg + 1] + s0b[4 * rg + 1]);
            float p2 = sigm2(s0a[4 * rg + 2] + s0b[4 * rg + 2]);
            float p3 = sigm2(s0a[4 * rg + 3] + s0b[4 * rg + 3]);
            W0[0][rg] = cvt_pk_bf16(p0, p1);
            W1[0][rg] = cvt_pk_bf16(p2, p3);
        }

        // ---- stage C: PV0 MFMAs || sigmoid1 ----
        __builtin_amdgcn_s_setprio(1);
        #pragma unroll
        for (int s2 = 0; s2 < 2; ++s2) {
            unsigned a0 = W0[0][2 * s2], b0 = W0[0][2 * s2 + 1];
            unsigned a1 = W1[0][2 * s2], b1 = W1[0][2 * s2 + 1];
            asm("v_permlane32_swap_b32 %0, %1" : "+v"(a0), "+v"(b0));
            asm("v_permlane32_swap_b32 %0, %1" : "+v"(a1), "+v"(b1));
            u32x4 pw;
            pw[0] = a0; pw[1] = a1; pw[2] = b0; pw[3] = b1;
            s16x8 pf = __builtin_bit_cast(s16x8, pw);
            #pragma unroll
            for (int ft = 0; ft < 4; ++ft) {
                s16x8 vf = *(const s16x8*)(Vl + (size_t)(32 * ft + l31) * VT_STR + s2 * 16 + g * 8);
                acc[ft] = __builtin_amdgcn_mfma_f32_32x32x16_bf16(pf, vf, acc[ft], 0, 0, 0);
            }
            #pragma unroll
            for (int h = 0; h < 2; ++h) {
                const int rg = 2 * s2 + h;
                float p0 = sigm2(s1a[4 * rg + 0] + s1b[4 * rg + 0]);
                float p1 = sigm2(s1a[4 * rg + 1] + s1b[4 * rg + 1]);
                float p2 = sigm2(s1a[4 * rg + 2] + s1b[4 * rg + 2]);
                float p3 = sigm2(s1a[4 * rg + 3] + s1b[4 * rg + 3]);
                W0[1][rg] = cvt_pk_bf16(p0, p1);
                W1[1][rg] = cvt_pk_bf16(p2, p3);
            }
        }

        // ---- stage D: PV1 ----
        #pragma unroll
        for (int s2 = 0; s2 < 2; ++s2) {
            unsigned a0 = W0[1][2 * s2], b0 = W0[1][2 * s2 + 1];
            unsigned a1 = W1[1][2 * s2], b1 = W1[1][2 * s2 + 1];
            asm("v_permlane32_swap_b32 %0, %1" : "+v"(a0), "+v"(b0));
            asm("v_permlane32_swap_b32 %0, %1" : "+v"(a1), "+v"(b1));
            u32x4 pw;
            pw[0] = a0; pw[1] = a1; pw[2] = b0; pw[3] = b1;
            s16x8 pf = __builtin_bit_cast(s16x8, pw);
            const int ks = 2 + s2;
            #pragma unroll
            for (int ft = 0; ft < 4; ++ft) {
                s16x8 vf = *(const s16x8*)(Vl + (size_t)(32 * ft + l31) * VT_STR + ks * 16 + g * 8);
                acc[ft] = __builtin_amdgcn_mfma_f32_32x32x16_bf16(pf, vf, acc[ft], 0, 0, 0);
            }
        }
        __builtin_amdgcn_s_setprio(0);

        // ---- write-late into other buffer ----
        if (pre) {
            unsigned short* Kd = (unsigned short*)(smem + (c ^ 1) * BUF_BYTES);
            unsigned short* Vd = (unsigned short*)(smem + (c ^ 1) * BUF_BYTES + KT_BYTES);
            #pragma unroll
            for (int i = 0; i < 4; ++i)
                *(s16x8*)(Kd + kDst + i * 16 * KT_STR) = kr[i];
            #pragma unroll
            for (int i = 0; i < 4; ++i)
                *(s16x8*)(Vd + vDst + i * 32 * VT_STR) = vr[i];
        }
        __syncthreads();
        c ^= 1;
    }

    // ---- epilogue: bf16x2-packed partial (row pairs r2, r2+1) ----
    unsigned* op = outp + (size_t)split * ((size_t)NBATCH * HWSZ * 64);
    #pragma unroll
    for (int ft = 0; ft < 4; ++ft)
    #pragma unroll
    for (int pr = 0; pr < 8; ++pr) {
        int r2 = 2 * pr;
        int row = (r2 & 3) + 8 * (r2 >> 2) + 4 * g;      // even
        int q = qb + 32 * qt + row;
        unsigned v = cvt_pk_bf16(acc[ft][r2], acc[ft][r2 + 1]);
        op[((size_t)(b * HWSZ + q) >> 1) * 128 + 32 * ft + l31] = v;
    }
}

// ---------------- Kernel 2b: QBLK=64 fallback (2-split / no-split) ----------------
template<bool SPLIT>
__global__ __launch_bounds__(256, 2) void attn_kernel(
    const unsigned short* __restrict__ Kbf,
    const unsigned short* __restrict__ Qbf,
    const unsigned short* __restrict__ Vtbf,
    const float* __restrict__ resid,
    float* __restrict__ outp)
{
    __shared__ __align__(16) char smem[2 * BUF_BYTES];

    const int t    = threadIdx.x;
    const int lane = t & 63;
    const int w    = t >> 6;
    const int qt   = w & 1;
    const int jt   = w >> 1;
    const int l31  = lane & 31;
    const int g    = lane >> 5;

    int bid = blockIdx.x;
    int half = 0;
    if (SPLIT) { half = bid >> 8; bid &= 255; }
    const int b      = bid >> 6;
    const int qb     = (bid & 63) * 64;
    const int jBegin = half * (HWSZ / 2);
    const int nt     = (SPLIT ? HWSZ / 2 : HWSZ) / 64;

    s16x8 qfrag[8];
    {
        const unsigned short* qp =
            Qbf + (((size_t)(b * HWSZ + qb + 32 * qt + l31)) << 7) + g * 8;
        #pragma unroll
        for (int fs = 0; fs < 8; ++fs)
            qfrag[fs] = *(const s16x8*)(qp + fs * 16);
    }

    f32x16 acc[4];
    #pragma unroll
    for (int ft = 0; ft < 4; ++ft)
        #pragma unroll
        for (int i = 0; i < 16; ++i) acc[ft][i] = 0.f;

    const unsigned short* Kbase = Kbf  + (((size_t)b * HWSZ) << 7);
    const unsigned short* Vbase = Vtbf + (((size_t)b) << 7) * HWSZ;

    const unsigned short* kSrc = Kbase + (size_t)(jBegin + (t >> 4)) * 128 + (t & 15) * 8;
    const unsigned short* vSrc = Vbase + (size_t)(t >> 3) * HWSZ + jBegin + (t & 7) * 8;
    const int kDst = (t >> 4) * KT_STR + (t & 15) * 8;
    const int vDst = (t >> 3) * VT_STR + (t & 7) * 8;

    {
        unsigned short* Kl = (unsigned short*)smem;
        unsigned short* Vl = (unsigned short*)(smem + KT_BYTES);
        #pragma unroll
        for (int i = 0; i < 4; ++i)
            *(s16x8*)(Kl + kDst + i * 16 * KT_STR) = *(const s16x8*)(kSrc + (size_t)i * 2048);
        #pragma unroll
        for (int i = 0; i < 4; ++i)
            *(s16x8*)(Vl + vDst + i * 32 * VT_STR) = *(const s16x8*)(vSrc + (size_t)i * 32 * HWSZ);
    }
    __syncthreads();

    int c = 0;
    for (int it = 0; it < nt; ++it) {
        const bool pre = (it + 1 < nt);
        s16x8 kr[4], vr[4];
        if (pre) {
            kSrc += 64 * 128;
            vSrc += 64;
            #pragma unroll
            for (int i = 0; i < 4; ++i)
                kr[i] = *(const s16x8*)(kSrc + (size_t)i * 2048);
            #pragma unroll
            for (int i = 0; i < 4; ++i)
                vr[i] = *(const s16x8*)(vSrc + (size_t)i * 32 * HWSZ);
        }

        const unsigned short* Kl = (const unsigned short*)(smem + c * BUF_BYTES);
        const unsigned short* Vl = (const unsigned short*)(smem + c * BUF_BYTES + KT_BYTES);

        f32x16 sa, sb;
        #pragma unroll
        for (int i = 0; i < 16; ++i) { sa[i] = 0.f; sb[i] = 0.f; }
        const unsigned short* Krow = Kl + (size_t)(32 * jt + l31) * KT_STR + g * 8;
        __builtin_amdgcn_s_setprio(1);
        #pragma unroll
        for (int fs = 0; fs < 4; ++fs) {
            sa = __builtin_amdgcn_mfma_f32_32x32x16_bf16(
                     *(const s16x8*)(Krow + fs * 16), qfrag[fs], sa, 0, 0, 0);
            sb = __builtin_amdgcn_mfma_f32_32x32x16_bf16(
                     *(const s16x8*)(Krow + (fs + 4) * 16), qfrag[fs + 4], sb, 0, 0, 0);
        }
        __builtin_amdgcn_s_setprio(0);

        unsigned W0[4], W1[4];
        #pragma unroll
        for (int rg = 0; rg < 4; ++rg) {
            float p0 = sigm2(sa[4 * rg + 0] + sb[4 * rg + 0]);
            float p1 = sigm2(sa[4 * rg + 1] + sb[4 * rg + 1]);
            float p2 = sigm2(sa[4 * rg + 2] + sb[4 * rg + 2]);
            float p3 = sigm2(sa[4 * rg + 3] + sb[4 * rg + 3]);
            W0[rg] = cvt_pk_bf16(p0, p1);
            W1[rg] = cvt_pk_bf16(p2, p3);
        }

        #pragma unroll
        for (int s2 = 0; s2 < 2; ++s2) {
            unsigned a0 = W0[2 * s2], b0 = W0[2 * s2 + 1];
            unsigned a1 = W1[2 * s2], b1 = W1[2 * s2 + 1];
            asm("v_permlane32_swap_b32 %0, %1" : "+v"(a0), "+v"(b0));
            asm("v_permlane32_swap_b32 %0, %1" : "+v"(a1), "+v"(b1));
            u32x4 pw;
            pw[0] = a0; pw[1] = a1; pw[2] = b0; pw[3] = b1;
            s16x8 pf = __builtin_bit_cast(s16x8, pw);
            const int ks = 2 * jt + s2;
            __builtin_amdgcn_s_setprio(1);
            #pragma unroll
            for (int ft = 0; ft < 4; ++ft) {
                s16x8 vf = *(const s16x8*)(Vl + (size_t)(32 * ft + l31) * VT_STR + ks * 16 + g * 8);
                acc[ft] = __builtin_amdgcn_mfma_f32_32x32x16_bf16(pf, vf, acc[ft], 0, 0, 0);
            }
            __builtin_amdgcn_s_setprio(0);
        }

        if (pre) {
            unsigned short* Kd = (unsigned short*)(smem + (c ^ 1) * BUF_BYTES);
            unsigned short* Vd = (unsigned short*)(smem + (c ^ 1) * BUF_BYTES + KT_BYTES);
            #pragma unroll
            for (int i = 0; i < 4; ++i)
                *(s16x8*)(Kd + kDst + i * 16 * KT_STR) = kr[i];
            #pragma unroll
            for (int i = 0; i < 4; ++i)
                *(s16x8*)(Vd + vDst + i * 32 * VT_STR) = vr[i];
        }
        __syncthreads();
        c ^= 1;
    }

    float* red = (float*)smem;
    if (jt == 1) {
        #pragma unroll
        for (int ft = 0; ft < 4; ++ft)
        #pragma unroll
        for (int r = 0; r < 16; ++r) {
            int row = (r & 3) + 8 * (r >> 2) + 4 * g;
            red[qt * 4096 + row * 128 + 32 * ft + l31] = acc[ft][r];
        }
    }
    __syncthreads();
    if (jt == 0) {
        float* op = outp + (SPLIT ? (size_t)half * ((size_t)NBATCH * HWSZ * 128) : 0);
        #pragma unroll
        for (int ft = 0; ft < 4; ++ft)
        #pragma unroll
        for (int r = 0; r < 16; ++r) {
            int row = (r & 3) + 8 * (r >> 2) + 4 * g;
            float v = acc[ft][r] + red[qt * 4096 + row * 128 + 32 * ft + l31];
            int q = qb + 32 * qt + row;
            size_t o = (((size_t)(b * HWSZ + q)) << 7) + 32 * ft + l31;
            if (SPLIT) op[o] = v;
            else       op[o] = v + resid[o];
        }
    }
}

// ---------------- Kernel 3: partial reduce + residual ----------------
__global__ __launch_bounds__(256, 1) void reduce2_kernel(
    const float* __restrict__ p0, const float* __restrict__ p1, float* outp)
{
    int i = blockIdx.x * 256 + threadIdx.x;
    f32x4 a = ((const f32x4*)p0)[i];
    f32x4 b = ((const f32x4*)p1)[i];
    f32x4 c = ((f32x4*)outp)[i];
    ((f32x4*)outp)[i] = a + b + c;
}

__global__ __launch_bounds__(256, 1) void reduce4bf_kernel(
    const unsigned* __restrict__ parts, const unsigned short* __restrict__ xqu,
    float* __restrict__ outp)
{
    const size_t NU = (size_t)NBATCH * HWSZ * 64;
    size_t j0 = ((size_t)blockIdx.x * 256 + threadIdx.x) * 4;
    f32x4 lo, hi;
    #pragma unroll
    for (int e = 0; e < 4; ++e) { lo[e] = 0.f; hi[e] = 0.f; }
    #pragma unroll
    for (int k = 0; k < 4; ++k) {
        u32x4 v = *(const u32x4*)(parts + k * NU + j0);
        #pragma unroll
        for (int e = 0; e < 4; ++e) {
            lo[e] += bf_lo(v[e]);
            hi[e] += bf_hi(v[e]);
        }
    }
    size_t p  = j0 >> 7;
    int    f0 = (int)(j0 & 127);
    size_t o0 = (p * 2) * 128 + f0;
    const ushort4 r0 = *(const ushort4*)(xqu + o0);
    const ushort4 r1 = *(const ushort4*)(xqu + o0 + 128);
    lo[0] += bf2f(r0.x); lo[1] += bf2f(r0.y); lo[2] += bf2f(r0.z); lo[3] += bf2f(r0.w);
    hi[0] += bf2f(r1.x); hi[1] += bf2f(r1.y); hi[2] += bf2f(r1.z); hi[3] += bf2f(r1.w);
    *(f32x4*)(outp + o0)       = lo;
    *(f32x4*)(outp + o0 + 128) = hi;
}

extern "C" void kernel_launch(void* const* d_in, const int* in_sizes, int n_in,
                              void* d_out, int out_size, void* d_ws, size_t ws_size,
                              hipStream_t stream) {
    const float* x  = (const float*)d_in[0];
    const float* y  = (const float*)d_in[1];
    const float* W1 = (const float*)d_in[2];
    const float* b1 = (const float*)d_in[3];
    const float* W2 = (const float*)d_in[4];
    const float* b2 = (const float*)d_in[5];
    float* out = (float*)d_out;

    const size_t NELEM = (size_t)NBATCH * HWSZ * 128;   // 2,097,152
    unsigned short* xq_bf  = (unsigned short*)d_ws;
    unsigned short* yk_bf  = xq_bf + NELEM;
    unsigned short* ykT_bf = yk_bf + NELEM;
    unsigned short* xqu_bf = ykT_bf + NELEM;
    unsigned* partu = (unsigned*)(xqu_bf + NELEM);
    float* part = (float*)(ykT_bf + NELEM);

    if (ws_size >= NELEM * 16) {                 // main: 4-split, bf16 partials+residual
        proj_kernel<false><<<(int)(NBATCH * HWSZ / 32), 256, 0, stream>>>(
            x, y, W1, b1, W2, b2, nullptr, xqu_bf, xq_bf, yk_bf, ykT_bf);
        attn128_kernel<<<512, 256, 0, stream>>>(xq_bf, yk_bf, ykT_bf, partu);
        reduce4bf_kernel<<<(int)(NELEM / 2048), 256, 0, stream>>>(partu, xqu_bf, out);
    } else if (ws_size >= NELEM * 14) {          // QBLK=64, 2-split (f32 partials)
        proj_kernel<true><<<(int)(NBATCH * HWSZ / 32), 256, 0, stream>>>(
            x, y, W1, b1, W2, b2, out, nullptr, xq_bf, yk_bf, ykT_bf);
        attn_kernel<true><<<512, 256, 0, stream>>>(xq_bf, yk_bf, ykT_bf, out, part);
        reduce2_kernel<<<(int)(NELEM / 1024), 256, 0, stream>>>(part, part + NELEM, out);
    } else {
        proj_kernel<true><<<(int)(NBATCH * HWSZ / 32), 256, 0, stream>>>(
            x, y, W1, b1, W2, b2, out, nullptr, xq_bf, yk_bf, ykT_bf);
        attn_kernel<false><<<256, 256, 0, stream>>>(xq_bf, yk_bf, ykT_bf, out, out);
    }
}